// Round 2
// baseline (72.818 us; speedup 1.0000x reference)
//
#include <hip/hip_runtime.h>
#include <math.h>

#define HD 256
#define SD 768
#define D2 512
#define NE 8
#define NB 32

__device__ __forceinline__ float gelu_exact(float x) {
    return 0.5f * x * (1.0f + erff(x * 0.70710678118654752f));
}

// ---------------------------------------------------------------------------
// K1: proj = smiles @ sW + sb. Writes proj[32][256] and fused[:, 256:512].
// grid (8 coltiles of 32 cols, 4 rowgroups of 8 rows), block 256 = 32c x 8r.
// sW tile staged to LDS via coalesced float4 (read ~once across grid).
__global__ __launch_bounds__(256) void k_proj(
    const float* __restrict__ smiles, const float* __restrict__ sW,
    const float* __restrict__ sb, float* __restrict__ proj,
    float* __restrict__ fused)
{
    int ct = blockIdx.x, rg = blockIdx.y, t = threadIdx.x;
    __shared__ float s_sm[8][SD];     // 24 KB
    __shared__ float s_w[256][32];    // 32 KB (k-chunk x 32 cols)

    {
        const float4* src = (const float4*)(smiles + (size_t)rg * 8 * SD);
        float4* dst = (float4*)&s_sm[0][0];
        for (int i = t; i < 8 * SD / 4; i += 256) dst[i] = src[i];
    }
    int c = t & 31, r = t >> 5;
    float a0 = 0.f, a1 = 0.f;
    for (int k0 = 0; k0 < SD; k0 += 256) {
        __syncthreads();
        for (int i = t; i < 256 * 8; i += 256) {   // 8 float4 per k-row
            int kk = i >> 3, f = i & 7;
            *(float4*)&s_w[kk][f * 4] =
                *(const float4*)(sW + (size_t)(k0 + kk) * HD + ct * 32 + f * 4);
        }
        __syncthreads();
        #pragma unroll 8
        for (int kk = 0; kk < 256; kk += 2) {
            a0 = fmaf(s_sm[r][k0 + kk],     s_w[kk][c],     a0);
            a1 = fmaf(s_sm[r][k0 + kk + 1], s_w[kk + 1][c], a1);
        }
    }
    int row = rg * 8 + r, col = ct * 32 + c;
    float val = a0 + a1 + sb[col];
    proj[row * HD + col] = val;
    fused[row * 2 * HD + HD + col] = val;   // fused second half = proj
}

// ---------------------------------------------------------------------------
// K2: per 2 rows: v = proj@Wv+bv, att = v@Wo+bo, fused[:,0:256] = att,
//     gate logits -> softmax -> top2. grid 16 blocks, block 256.
//     Wv/Wo staged to LDS in 64-k chunks (contiguous -> coalesced float4).
__global__ __launch_bounds__(256) void k_rowchain(
    const float* __restrict__ proj, const float* __restrict__ Wv,
    const float* __restrict__ bv, const float* __restrict__ Wo,
    const float* __restrict__ bo, const float* __restrict__ gW,
    const float* __restrict__ gb, float* __restrict__ fused,
    float* __restrict__ probs_out, float* __restrict__ p_out,
    int* __restrict__ sel_out)
{
    int b0 = blockIdx.x * 2, t = threadIdx.x;
    __shared__ float s_w[64][HD];     // 64 KB chunk buffer
    __shared__ float s_gw[D2 * NE];   // 16 KB
    __shared__ float s_p[2][HD];
    __shared__ float s_v[2][HD];
    __shared__ float s_f[2][2 * HD];
    __shared__ float s_red[256];
    __shared__ float s_gate[2][NE];

    for (int i = t; i < D2 * NE / 4; i += 256)
        ((float4*)s_gw)[i] = ((const float4*)gW)[i];
    for (int i = t; i < 2 * HD / 4; i += 256)
        ((float4*)&s_p[0][0])[i] = ((const float4*)(proj + (size_t)b0 * HD))[i];

    // ---- v = proj @ Wv ----
    float v0 = 0.f, v1 = 0.f;
    for (int k0 = 0; k0 < HD; k0 += 64) {
        __syncthreads();
        const float4* src = (const float4*)(Wv + (size_t)k0 * HD);
        float4* dst = (float4*)&s_w[0][0];
        for (int i = t; i < 64 * HD / 4; i += 256) dst[i] = src[i];
        __syncthreads();
        #pragma unroll 8
        for (int kk = 0; kk < 64; ++kk) {
            float w = s_w[kk][t];
            v0 = fmaf(s_p[0][k0 + kk], w, v0);
            v1 = fmaf(s_p[1][k0 + kk], w, v1);
        }
    }
    __syncthreads();
    s_v[0][t] = v0 + bv[t];
    s_v[1][t] = v1 + bv[t];

    // ---- att = v @ Wo ----
    float o0 = 0.f, o1 = 0.f;
    for (int k0 = 0; k0 < HD; k0 += 64) {
        __syncthreads();
        const float4* src = (const float4*)(Wo + (size_t)k0 * HD);
        float4* dst = (float4*)&s_w[0][0];
        for (int i = t; i < 64 * HD / 4; i += 256) dst[i] = src[i];
        __syncthreads();
        #pragma unroll 8
        for (int kk = 0; kk < 64; ++kk) {
            float w = s_w[kk][t];
            o0 = fmaf(s_v[0][k0 + kk], w, o0);
            o1 = fmaf(s_v[1][k0 + kk], w, o1);
        }
    }
    o0 += bo[t]; o1 += bo[t];
    s_f[0][t] = o0;  s_f[0][HD + t] = s_p[0][t];
    s_f[1][t] = o1;  s_f[1][HD + t] = s_p[1][t];
    fused[(size_t)(b0 + 0) * 2 * HD + t] = o0;
    fused[(size_t)(b0 + 1) * 2 * HD + t] = o1;
    __syncthreads();

    // ---- gate logits: t = row*128 + ch*8 + e, ch covers 32 d's ----
    int row = t >> 7, l = t & 127, e = l & 7, ch = l >> 3;
    float gp = 0.f;
    #pragma unroll
    for (int j = 0; j < 32; ++j) {
        int d = ch * 32 + j;
        gp = fmaf(s_f[row][d], s_gw[d * NE + e], gp);
    }
    s_red[t] = gp;
    __syncthreads();
    for (int off = 64; off >= 8; off >>= 1) {
        if ((t & 127) < off) s_red[t] += s_red[t + off];
        __syncthreads();
    }
    if ((t & 127) < NE) s_gate[row][l] = s_red[t] + gb[l];
    __syncthreads();

    if ((t & 127) == 0) {
        int b = b0 + row;
        float m = s_gate[row][0];
        for (int i = 1; i < NE; ++i) m = fmaxf(m, s_gate[row][i]);
        float ex[NE], ssum = 0.f;
        for (int i = 0; i < NE; ++i) { ex[i] = expf(s_gate[row][i] - m); ssum += ex[i]; }
        float pr[NE];
        for (int i = 0; i < NE; ++i) { pr[i] = ex[i] / ssum; probs_out[b * NE + i] = pr[i]; }
        int i1 = 0;
        for (int i = 1; i < NE; ++i) if (pr[i] > pr[i1]) i1 = i;
        int i2 = (i1 == 0) ? 1 : 0;
        for (int i = 0; i < NE; ++i) if (i != i1 && pr[i] > pr[i2]) i2 = i;
        float p1 = pr[i1], p2 = pr[i2], s12 = p1 + p2;
        sel_out[b * 2 + 0] = i1;
        sel_out[b * 2 + 1] = i2;
        p_out[b * 2 + 0] = p1 / s12;
        p_out[b * 2 + 1] = p2 / s12;
    }
}

// ---------------------------------------------------------------------------
// K3: h1 = gelu(fused @ W1[e] + b1[e]). grid (8 experts, 32 coltiles of 16),
// block 256 = 16 cols x 16 rowgroups (2 rows each). W1 read exactly once.
__global__ __launch_bounds__(256) void k_h1(
    const float* __restrict__ fused, const float* __restrict__ W1,
    const float* __restrict__ b1, float* __restrict__ h1)
{
    int e = blockIdx.x, ct = blockIdx.y, t = threadIdx.x;
    __shared__ float s_f[NB][D2 + 8];   // 66.6 KB (pad 8 -> 2-way banks, free)
    __shared__ float s_w[D2][16];       // 32 KB

    {
        const float4* src = (const float4*)fused;
        for (int i = t; i < NB * D2 / 4; i += 256) {
            int row = i >> 7, f = i & 127;
            *(float4*)&s_f[row][f * 4] = src[i];
        }
    }
    {
        const float* W = W1 + (size_t)e * D2 * D2 + ct * 16;
        for (int i = t; i < D2 * 4; i += 256) {
            int kk = i >> 2, f = i & 3;
            *(float4*)&s_w[kk][f * 4] = *(const float4*)(W + (size_t)kk * D2 + f * 4);
        }
    }
    __syncthreads();
    int c = t & 15, rg = t >> 4, r0 = rg * 2, r1 = r0 + 1;
    float a0 = 0.f, a1 = 0.f, a2 = 0.f, a3 = 0.f;
    #pragma unroll 8
    for (int k = 0; k < D2; k += 2) {
        float w0 = s_w[k][c], w1 = s_w[k + 1][c];
        a0 = fmaf(s_f[r0][k], w0, a0);  a1 = fmaf(s_f[r0][k + 1], w1, a1);
        a2 = fmaf(s_f[r1][k], w0, a2);  a3 = fmaf(s_f[r1][k + 1], w1, a3);
    }
    int col = ct * 16 + c;
    float bias = b1[e * D2 + col];
    h1[((size_t)e * NB + r0) * D2 + col] = gelu_exact(a0 + a1 + bias);
    h1[((size_t)e * NB + r1) * D2 + col] = gelu_exact(a2 + a3 + bias);
}

// ---------------------------------------------------------------------------
// K4: eo = h1 @ W2[e] + b2[e]. grid (8 experts, 16 coltiles of 16), block 256.
__global__ __launch_bounds__(256) void k_out(
    const float* __restrict__ h1, const float* __restrict__ W2,
    const float* __restrict__ b2, float* __restrict__ eo)
{
    int e = blockIdx.x, ct = blockIdx.y, t = threadIdx.x;
    __shared__ float s_h[NB][D2 + 8];
    __shared__ float s_w[D2][16];

    {
        const float4* src = (const float4*)(h1 + (size_t)e * NB * D2);
        for (int i = t; i < NB * D2 / 4; i += 256) {
            int row = i >> 7, f = i & 127;
            *(float4*)&s_h[row][f * 4] = src[i];
        }
    }
    {
        const float* W = W2 + (size_t)e * D2 * HD + ct * 16;
        for (int i = t; i < D2 * 4; i += 256) {
            int kk = i >> 2, f = i & 3;
            *(float4*)&s_w[kk][f * 4] = *(const float4*)(W + (size_t)kk * HD + f * 4);
        }
    }
    __syncthreads();
    int c = t & 15, rg = t >> 4, r0 = rg * 2, r1 = r0 + 1;
    float a0 = 0.f, a1 = 0.f, a2 = 0.f, a3 = 0.f;
    #pragma unroll 8
    for (int k = 0; k < D2; k += 2) {
        float w0 = s_w[k][c], w1 = s_w[k + 1][c];
        a0 = fmaf(s_h[r0][k], w0, a0);  a1 = fmaf(s_h[r0][k + 1], w1, a1);
        a2 = fmaf(s_h[r1][k], w0, a2);  a3 = fmaf(s_h[r1][k + 1], w1, a3);
    }
    int col = ct * 16 + c;
    float bias = b2[e * HD + col];
    eo[((size_t)e * NB + r0) * HD + col] = a0 + a1 + bias;
    eo[((size_t)e * NB + r1) * HD + col] = a2 + a3 + bias;
}

// ---------------------------------------------------------------------------
// K5: gather top-2, combine, LayerNorm, classifier; block 0 computes aux.
__global__ __launch_bounds__(256) void finalize(
    const float* __restrict__ eout, const float* __restrict__ probs,
    const float* __restrict__ pnorm, const int* __restrict__ sel,
    const float* __restrict__ lng, const float* __restrict__ lnb,
    const float* __restrict__ clsW, const float* __restrict__ clsb,
    float* __restrict__ out)
{
    int b = blockIdx.x, t = threadIdx.x;
    __shared__ float s_red[256];
    __shared__ float s_stats[4];

    int e0 = sel[b * 2 + 0], e1 = sel[b * 2 + 1];
    float p0 = pnorm[b * 2 + 0], p1 = pnorm[b * 2 + 1];
    float moe = p0 * eout[((size_t)e0 * NB + b) * HD + t]
              + p1 * eout[((size_t)e1 * NB + b) * HD + t];

    s_red[t] = moe; __syncthreads();
    for (int off = 128; off > 0; off >>= 1) {
        if (t < off) s_red[t] += s_red[t + off];
        __syncthreads();
    }
    if (t == 0) s_stats[0] = s_red[0] * (1.f / HD);
    __syncthreads();
    float mu = s_stats[0];
    float d = moe - mu;

    s_red[t] = d * d; __syncthreads();
    for (int off = 128; off > 0; off >>= 1) {
        if (t < off) s_red[t] += s_red[t + off];
        __syncthreads();
    }
    if (t == 0) s_stats[1] = s_red[0] * (1.f / HD);
    __syncthreads();

    float xn = d * rsqrtf(s_stats[1] + 1e-5f);
    float y = fmaf(xn, lng[t], lnb[t]);

    s_red[t] = y * clsW[t * 2 + 0]; __syncthreads();
    for (int off = 128; off > 0; off >>= 1) {
        if (t < off) s_red[t] += s_red[t + off];
        __syncthreads();
    }
    if (t == 0) s_stats[2] = s_red[0] + clsb[0];
    __syncthreads();

    s_red[t] = y * clsW[t * 2 + 1]; __syncthreads();
    for (int off = 128; off > 0; off >>= 1) {
        if (t < off) s_red[t] += s_red[t + off];
        __syncthreads();
    }
    if (t == 0) {
        out[b * 2 + 0] = s_stats[2];
        out[b * 2 + 1] = s_red[0] + clsb[1];
    }

    if (blockIdx.x == 0) {
        __syncthreads();
        s_red[t] = probs[t];
        __syncthreads();
        for (int off = 128; off >= 8; off >>= 1) {
            if (t < off) s_red[t] += s_red[t + off];
            __syncthreads();
        }
        if (t == 0) {
            float aux = 0.f;
            for (int e = 0; e < NE; ++e) {
                float u = s_red[e] * (1.f / 32.f);
                aux += u * logf(0.125f) - logf(u) * 0.125f;
            }
            out[64] = 0.1f * aux;
        }
    }
}

extern "C" void kernel_launch(void* const* d_in, const int* in_sizes, int n_in,
                              void* d_out, int out_size, void* d_ws, size_t ws_size,
                              hipStream_t stream) {
    (void)in_sizes; (void)n_in; (void)out_size; (void)ws_size;
    const float* smiles = (const float*)d_in[2];
    const float* sW  = (const float*)d_in[7];
    const float* sb  = (const float*)d_in[8];
    const float* Wv  = (const float*)d_in[13];
    const float* bv  = (const float*)d_in[14];
    const float* Wo  = (const float*)d_in[15];
    const float* bo  = (const float*)d_in[16];
    const float* gW  = (const float*)d_in[17];
    const float* gb  = (const float*)d_in[18];
    const float* W1  = (const float*)d_in[19];
    const float* b1  = (const float*)d_in[20];
    const float* W2  = (const float*)d_in[21];
    const float* b2  = (const float*)d_in[22];
    const float* lng = (const float*)d_in[23];
    const float* lnb = (const float*)d_in[24];
    const float* cW  = (const float*)d_in[25];
    const float* cb  = (const float*)d_in[26];
    float* out = (float*)d_out;
    float* ws  = (float*)d_ws;

    float* proj  = ws;                        // 32*256   = 8192
    float* fused = ws + 8192;                 // 32*512   = 16384
    float* probs = ws + 24576;                // 32*8     = 256
    float* pn    = ws + 24832;                // 32*2     = 64
    int*   sel   = (int*)(ws + 24896);        // 32*2     = 64
    float* h1    = ws + 24960;                // 8*32*512 = 131072
    float* eo    = ws + 156032;               // 8*32*256 = 65536

    k_proj<<<dim3(8, 4), 256, 0, stream>>>(smiles, sW, sb, proj, fused);
    k_rowchain<<<16, 256, 0, stream>>>(proj, Wv, bv, Wo, bo, gW, gb,
                                       fused, probs, pn, sel);
    k_h1<<<dim3(8, 32), 256, 0, stream>>>(fused, W1, b1, h1);
    k_out<<<dim3(8, 16), 256, 0, stream>>>(h1, W2, b2, eo);
    finalize<<<32, 256, 0, stream>>>(eo, probs, pn, sel, lng, lnb, cW, cb, out);
}